// Round 6
// baseline (1052.013 us; speedup 1.0000x reference)
//
#include <hip/hip_runtime.h>
#include <math.h>

#define B_ 16
#define N_ 256
#define L_ 32
#define NN_ (N_*N_)          // 65536
#define NNL_ (NN_*L_)        // 2097152 elements per batch
#define ANN_ (B_*NN_)        // 1048576
#define POTS_OFF 4096        // float offset where big arrays start
#define NEGINF -1.0e30f
#define LOG2E_F 1.4426950408889634f
#define LN2_F   0.6931471805599453f

// Fast base-2 transcendentals (v_exp_f32 / v_log_f32). Math verified r2/r3.
#if __has_builtin(__builtin_amdgcn_exp2f)
#define EX2(x) __builtin_amdgcn_exp2f(x)
#else
#define EX2(x) exp2f(x)
#endif
#if __has_builtin(__builtin_amdgcn_logf)
#define LG2(x) __builtin_amdgcn_logf(x)
#else
#define LG2(x) log2f(x)
#endif

// ws float layout (float* W = (float*)d_ws):
//   [0 .. 2048)  : 1024 doubles — stats partials [B][32][2]
//   [2048..2080) : stats (mean, invstd) per batch
//   W + POTS_OFF + k*ANN_:
//     0: pot1 (start-major, log2 units)   1: sbar (start-major, nat units)
//     2: pot2 (log2)   3: pot3 (log2)
//     4-5: EG2 p0 — float2 (ev,h) END-major chart
//     6: SG_h p0 (start-major h)
//     7: EG p1   8: EG p2
//   W + POTS_OFF + 9*ANN_: zres[64]
//
// r3-verified structure (567-574us): 48 blocks x 1024 threads. LEFT ev chart
// in LDS (triangular start-major, granule-XOR swizzled, ds_read_b128); RIGHT
// operands from global end-major rows (contiguous, L2-hot). One __syncthreads
// per width step.
// r4 lesson: explicit while-loop pipelining REGRESSED (compiler schedules the
// plain loop better). r5 lesson: halving rescale exp2s was NEUTRAL — the hot
// loop is latency-exposed, not arithmetic-bound.
// r6: TWO CELLS PER GROUP with independent (m,s,n) chains interleaved in one
// granule loop — 2x memory-level parallelism, half the serial chain depth,
// same per-lane VALU (group table on pairs=ceil(cells/2)).

// ---------------- kernel 1a: per-batch sum/sumsq partials ----------------
__global__ void stats_partial(const float* __restrict__ lp, double* __restrict__ part) {
    int blk = blockIdx.x;            // 0..511 = B*32
    int b = blk >> 5, seg = blk & 31;
    const float4* p4 = (const float4*)(lp + (size_t)b * NNL_ + (size_t)seg * (NNL_ / 32));
    double s = 0.0, ss = 0.0;
    for (int idx = threadIdx.x; idx < (NNL_ / 32 / 4); idx += 256) {
        float4 v = p4[idx];
        s  += (double)v.x + (double)v.y + (double)v.z + (double)v.w;
        ss += (double)v.x * v.x + (double)v.y * v.y + (double)v.z * v.z + (double)v.w * v.w;
    }
    __shared__ double sh0[256], sh1[256];
    sh0[threadIdx.x] = s; sh1[threadIdx.x] = ss;
    __syncthreads();
    for (int off = 128; off > 0; off >>= 1) {
        if (threadIdx.x < off) {
            sh0[threadIdx.x] += sh0[threadIdx.x + off];
            sh1[threadIdx.x] += sh1[threadIdx.x + off];
        }
        __syncthreads();
    }
    if (threadIdx.x == 0) { part[blk * 2] = sh0[0]; part[blk * 2 + 1] = sh1[0]; }
}

// ---------------- kernel 1b: finalize mean/invstd ----------------
__global__ void stats_final(const double* __restrict__ part, float* __restrict__ stats) {
    int b = threadIdx.x;
    if (b >= B_) return;
    double s = 0.0, ss = 0.0;
    for (int k = 0; k < 32; ++k) { s += part[(b * 32 + k) * 2]; ss += part[(b * 32 + k) * 2 + 1]; }
    double n = (double)NNL_;
    double mean = s / n;
    double var = (ss - s * s / n) / (n - 1.0);
    stats[b * 2]     = (float)mean;
    stats[b * 2 + 1] = (float)(1.0 / sqrt(var));
}

// ---------------- kernel 2: label-lse -> span potentials ----------------
__global__ __launch_bounds__(256)
void pots_kernel(const float* __restrict__ lp, const float* __restrict__ evm,
                 const float* __restrict__ stats, float* __restrict__ W) {
    int t = blockIdx.x * 256 + threadIdx.x;     // 0 .. B*NN-1
    int b = t >> 16;
    int rem = t & (NN_ - 1);
    int i = rem >> 8;
    int w = rem & (N_ - 1);
    if (i + w >= N_) return;
    int j = i + w;
    const float4* xp = (const float4*)(lp  + ((size_t)(b * NN_ + i * N_ + j) << 5));
    const float4* ep = (const float4*)(evm + ((size_t)(b * NN_ + i * N_ + j) << 5));
    float mean = stats[b * 2], invstd = stats[b * 2 + 1];
    float m1 = NEGINF, s1 = 0.f, n1 = 0.f;
    float m2 = NEGINF, s2 = 0.f;
    float m3 = NEGINF, s3 = 0.f;
#pragma unroll
    for (int c = 0; c < 8; ++c) {
        float4 xv = xp[c];
        float4 em = ep[c];
        float x0 = (xv.x - mean) * invstd, x1 = (xv.y - mean) * invstd;
        float x2 = (xv.z - mean) * invstd, x3 = (xv.w - mean) * invstd;
        {
            float cm = fmaxf(fmaxf(x0, x1), fmaxf(x2, x3));
            float nm = fmaxf(m1, cm);
            float sc = __expf(m1 - nm);
            float e0 = __expf(x0 - nm), e1 = __expf(x1 - nm);
            float e2 = __expf(x2 - nm), e3 = __expf(x3 - nm);
            s1 = s1 * sc + (e0 + e1 + e2 + e3);
            n1 = n1 * sc + (e0 * x0 + e1 * x1 + e2 * x2 + e3 * x3);
            m1 = nm;
        }
        {
            float y0 = x0 + __logf(fmaf(em.x, 0.9f, 0.1f) + 1e-10f);
            float y1 = x1 + __logf(fmaf(em.y, 0.9f, 0.1f) + 1e-10f);
            float y2 = x2 + __logf(fmaf(em.z, 0.9f, 0.1f) + 1e-10f);
            float y3 = x3 + __logf(fmaf(em.w, 0.9f, 0.1f) + 1e-10f);
            float cm = fmaxf(fmaxf(y0, y1), fmaxf(y2, y3));
            float nm = fmaxf(m2, cm);
            float sc = __expf(m2 - nm);
            s2 = s2 * sc + __expf(y0 - nm) + __expf(y1 - nm) + __expf(y2 - nm) + __expf(y3 - nm);
            m2 = nm;
        }
        {
            float z0 = fmaf(em.x, 1e6f, x0 - 1e6f);
            float z1 = fmaf(em.y, 1e6f, x1 - 1e6f);
            float z2 = fmaf(em.z, 1e6f, x2 - 1e6f);
            float z3 = fmaf(em.w, 1e6f, x3 - 1e6f);
            float cm = fmaxf(fmaxf(z0, z1), fmaxf(z2, z3));
            float nm = fmaxf(m3, cm);
            float sc = __expf(m3 - nm);
            s3 = s3 * sc + __expf(z0 - nm) + __expf(z1 - nm) + __expf(z2 - nm) + __expf(z3 - nm);
            m3 = nm;
        }
    }
    int o = b * NN_ + i * N_ + w;                // START-major layout
    W[POTS_OFF + 0 * ANN_ + o] = (m1 + __logf(s1)) * LOG2E_F;
    W[POTS_OFF + 1 * ANN_ + o] = n1 / s1;
    W[POTS_OFF + 2 * ANN_ + o] = (m2 + __logf(s2)) * LOG2E_F;
    W[POTS_OFF + 3 * ANN_ + o] = (m3 + __logf(s3)) * LOG2E_F;
}

// ---------------- LDS triangular chart addressing ----------------
// Start-major: row i holds widths u = 0..(255-i), capacity padded to 32-float
// (8-granule) multiples: cap32(i) = 32*(8 - (i>>5)). Total = 36864 floats
// (144 KB). Swizzle: granule index XOR (i&7) — stays in-row because capacity
// is a multiple of 8 granules; keeps 16B alignment for ds_read_b128.
__device__ __forceinline__ int lds_base(int i) {
    int a = i >> 5, c = i & 31;
    return ((8 * a - ((a * (a - 1)) >> 1)) << 10) + ((c * (8 - a)) << 5);
}
__device__ __forceinline__ int lds_addr(int i, int u) {
    return lds_base(i) + ((((u >> 2) ^ (i & 7)) << 2) | (u & 3));
}

// unaligned (4B-aligned) 16B global load
__device__ __forceinline__ float4 ld4u(const float* p) {
    float4 v; __builtin_memcpy(&v, p, 16); return v;
}

// ---------------- one width step, two cells per group ----------------
// NG = 1024>>LOGG groups of G lanes. Group g owns cells iA=g and iB=g+NG
// (strided pairing keeps both alive for most steps). Lane l walks granules
// mu = l, l+G, ... for BOTH cells with independent (m,s,n) chains — 2x MLP,
// half the serial softmax-chain depth, same per-lane arithmetic as r5.
// Right side p0: (ev,h) float2 end-major window (8 floats / granule).
// Masked tail granule (w&3 splits) handled by owner lane per cell.
template <bool EXPM, int LOGG>
__device__ __forceinline__ void stepw2(
    float* __restrict__ SL,
    const float* __restrict__ pot, const float* __restrict__ sbr,
    float* __restrict__ EG,      // p0: float2 (ev,h) chart; p1/p2: float chart
    float* __restrict__ SGh,
    const int w, const int cells, const int tid)
{
    constexpr int G  = 1 << LOGG;
    constexpr int NG = 1024 >> LOGG;
    const int g = tid >> LOGG;
    const int l = tid & (G - 1);
    if (g >= cells) return;
    const int iA = g;
    const int iB = g + NG;
    const bool hasB = (iB < cells);

    const int jA = iA + w, jB = iB + w;
    const int ibA = lds_base(iA), ibB = lds_base(iB);
    const int swA = iA & 7, swB = iB & 7;
    const float* egA = EG + (EXPM ? ((jA * N_) << 1) : (jA * N_));
    const float* egB = EG + (EXPM ? ((jB * N_) << 1) : (jB * N_));
    const float* shA = SGh + iA * N_;
    const float* shB = SGh + iB * N_;
    // epilogue inputs (rows always in-bounds even for inactive iB)
    const float pwA = pot[iA * N_ + w];
    const float pwB = pot[iB * N_ + w];
    float sbA = 0.f, sbB = 0.f;
    if constexpr (EXPM) { sbA = sbr[iA * N_ + w]; sbB = sbr[iB * N_ + w]; }

    const int F = w >> 2;        // full granules
    const int r = w & 3;         // tail valid count (0 => no tail)

    float mA = NEGINF, sA = 0.f, nA = 0.f;
    float mB = NEGINF, sB = 0.f, nB = 0.f;

    for (int mu = l; mu < F; mu += G) {
        const int u0 = mu << 2;
        // ---- loads, both cells (independent addresses -> parallel in flight)
        const float4 LvA = *(const float4*)&SL[ibA + ((mu ^ swA) << 2)];
        float4 P0A, P1A, HlA, RvA;
        if constexpr (EXPM) {
            P0A = ld4u(egA + ((w - 4 - u0) << 1));
            P1A = ld4u(egA + ((w - 4 - u0) << 1) + 4);
            HlA = *(const float4*)(shA + u0);
        } else {
            RvA = ld4u(egA + (w - 4 - u0));
        }
        float4 LvB, P0B, P1B, HlB, RvB;
        if (hasB) {
            LvB = *(const float4*)&SL[ibB + ((mu ^ swB) << 2)];
            if constexpr (EXPM) {
                P0B = ld4u(egB + ((w - 4 - u0) << 1));
                P1B = ld4u(egB + ((w - 4 - u0) << 1) + 4);
                HlB = *(const float4*)(shB + u0);
            } else {
                RvB = ld4u(egB + (w - 4 - u0));
            }
        }
        // ---- compute A
        {
            float e0, e1, e2, e3, h0, h1, h2, h3;
            if constexpr (EXPM) {
                e0 = LvA.x + P1A.z; e1 = LvA.y + P1A.x; e2 = LvA.z + P0A.z; e3 = LvA.w + P0A.x;
                h0 = HlA.x + P1A.w; h1 = HlA.y + P1A.y; h2 = HlA.z + P0A.w; h3 = HlA.w + P0A.y;
            } else {
                e0 = LvA.x + RvA.w; e1 = LvA.y + RvA.z; e2 = LvA.z + RvA.y; e3 = LvA.w + RvA.x;
            }
            float cm = fmaxf(fmaxf(e0, e1), fmaxf(e2, e3));
            float nm = fmaxf(mA, cm);
            float sc = EX2(mA - nm);
            float E0 = EX2(e0 - nm), E1 = EX2(e1 - nm), E2 = EX2(e2 - nm), E3 = EX2(e3 - nm);
            sA = sA * sc + ((E0 + E1) + (E2 + E3));
            if constexpr (EXPM)
                nA = nA * sc + ((E0 * h0 + E1 * h1) + (E2 * h2 + E3 * h3));
            mA = nm;
        }
        // ---- compute B
        if (hasB) {
            float e0, e1, e2, e3, h0, h1, h2, h3;
            if constexpr (EXPM) {
                e0 = LvB.x + P1B.z; e1 = LvB.y + P1B.x; e2 = LvB.z + P0B.z; e3 = LvB.w + P0B.x;
                h0 = HlB.x + P1B.w; h1 = HlB.y + P1B.y; h2 = HlB.z + P0B.w; h3 = HlB.w + P0B.y;
            } else {
                e0 = LvB.x + RvB.w; e1 = LvB.y + RvB.z; e2 = LvB.z + RvB.y; e3 = LvB.w + RvB.x;
            }
            float cm = fmaxf(fmaxf(e0, e1), fmaxf(e2, e3));
            float nm = fmaxf(mB, cm);
            float sc = EX2(mB - nm);
            float E0 = EX2(e0 - nm), E1 = EX2(e1 - nm), E2 = EX2(e2 - nm), E3 = EX2(e3 - nm);
            sB = sB * sc + ((E0 + E1) + (E2 + E3));
            if constexpr (EXPM)
                nB = nB * sc + ((E0 * h0 + E1 * h1) + (E2 * h2 + E3 * h3));
            mB = nm;
        }
    }

    // ---- masked tail granule (index F, r valid splits), one owner lane ----
    // Window starts before row j (row j-1 tail garbage; j>=1 keeps in-array);
    // invalid slots masked to NEGINF / h=0 (0*Inf would be NaN).
    if (r && l == (F & (G - 1))) {
        const int u0 = F << 2;
        {
            const float4 Lv = *(const float4*)&SL[ibA + ((F ^ swA) << 2)];
            float e0, e1, e2, h0 = 0.f, h1 = 0.f, h2 = 0.f;
            if constexpr (EXPM) {
                const float4 P0 = ld4u(egA + ((w - 4 - u0) << 1));
                const float4 P1 = ld4u(egA + ((w - 4 - u0) << 1) + 4);
                const float4 Hl = *(const float4*)(shA + u0);
                e0 = Lv.x + P1.z; e1 = Lv.y + P1.x; e2 = Lv.z + P0.z;
                h0 = Hl.x + P1.w; h1 = Hl.y + P1.y; h2 = Hl.z + P0.w;
            } else {
                const float4 Rv = ld4u(egA + (w - 4 - u0));
                e0 = Lv.x + Rv.w; e1 = Lv.y + Rv.z; e2 = Lv.z + Rv.y;
            }
            if (r < 2) { e1 = NEGINF; h1 = 0.f; }
            if (r < 3) { e2 = NEGINF; h2 = 0.f; }
            float cm = fmaxf(fmaxf(e0, e1), e2);
            float nm = fmaxf(mA, cm);
            float sc = EX2(mA - nm);
            float E0 = EX2(e0 - nm), E1 = EX2(e1 - nm), E2 = EX2(e2 - nm);
            sA = sA * sc + ((E0 + E1) + E2);
            if constexpr (EXPM) nA = nA * sc + ((E0 * h0 + E1 * h1) + E2 * h2);
            mA = nm;
        }
        if (hasB) {
            const float4 Lv = *(const float4*)&SL[ibB + ((F ^ swB) << 2)];
            float e0, e1, e2, h0 = 0.f, h1 = 0.f, h2 = 0.f;
            if constexpr (EXPM) {
                const float4 P0 = ld4u(egB + ((w - 4 - u0) << 1));
                const float4 P1 = ld4u(egB + ((w - 4 - u0) << 1) + 4);
                const float4 Hl = *(const float4*)(shB + u0);
                e0 = Lv.x + P1.z; e1 = Lv.y + P1.x; e2 = Lv.z + P0.z;
                h0 = Hl.x + P1.w; h1 = Hl.y + P1.y; h2 = Hl.z + P0.w;
            } else {
                const float4 Rv = ld4u(egB + (w - 4 - u0));
                e0 = Lv.x + Rv.w; e1 = Lv.y + Rv.z; e2 = Lv.z + Rv.y;
            }
            if (r < 2) { e1 = NEGINF; h1 = 0.f; }
            if (r < 3) { e2 = NEGINF; h2 = 0.f; }
            float cm = fmaxf(fmaxf(e0, e1), e2);
            float nm = fmaxf(mB, cm);
            float sc = EX2(mB - nm);
            float E0 = EX2(e0 - nm), E1 = EX2(e1 - nm), E2 = EX2(e2 - nm);
            sB = sB * sc + ((E0 + E1) + E2);
            if constexpr (EXPM) nB = nB * sc + ((E0 * h0 + E1 * h1) + E2 * h2);
            mB = nm;
        }
    }

    // ---- merge across the G lanes of the group ----
#pragma unroll
    for (int k = 1; k < G; k <<= 1) {
        {
            float mo = __shfl_xor(mA, k);
            float so = __shfl_xor(sA, k);
            float no = 0.f;
            if constexpr (EXPM) no = __shfl_xor(nA, k);
            float nm = fmaxf(mA, mo);
            float a  = EX2(mA - nm), bb = EX2(mo - nm);
            sA = sA * a + so * bb;
            if constexpr (EXPM) nA = nA * a + no * bb;
            mA = nm;
        }
        if (hasB) {
            float mo = __shfl_xor(mB, k);
            float so = __shfl_xor(sB, k);
            float no = 0.f;
            if constexpr (EXPM) no = __shfl_xor(nB, k);
            float nm = fmaxf(mB, mo);
            float a  = EX2(mB - nm), bb = EX2(mo - nm);
            sB = sB * a + so * bb;
            if constexpr (EXPM) nB = nB * a + no * bb;
            mB = nm;
        }
    }
    if (l == 0) {
        float vA = pwA + mA + LG2(sA);
        SL[lds_addr(iA, w)] = vA;
        if constexpr (EXPM) {
            float hvA = sbA + nA / sA;
            ((float2*)EG)[jA * N_ + w] = make_float2(vA, hvA);
            SGh[iA * N_ + w] = hvA;
        } else {
            EG[jA * N_ + w] = vA;
        }
        if (hasB) {
            float vB = pwB + mB + LG2(sB);
            SL[lds_addr(iB, w)] = vB;
            if constexpr (EXPM) {
                float hvB = sbB + nB / sB;
                ((float2*)EG)[jB * N_ + w] = make_float2(vB, hvB);
                SGh[iB * N_ + w] = hvB;
            } else {
                EG[jB * N_ + w] = vB;
            }
        }
    }
}

template <bool EXPM>
__device__ __forceinline__ void cky_loop(
    float* __restrict__ SL,
    const float* __restrict__ pot, const float* __restrict__ sbr,
    float* __restrict__ EG, float* __restrict__ SGh,
    const int len, const int tid)
{
    // width-0 diagonal
    for (int i = tid; i < len; i += 1024) {
        float v = pot[i * N_];
        SL[lds_addr(i, 0)] = v;
        if constexpr (EXPM) {
            float h0 = sbr[i * N_];
            ((float2*)EG)[i * N_] = make_float2(v, h0);
            SGh[i * N_] = h0;
        } else {
            EG[i * N_] = v;
        }
    }
    __syncthreads();
    for (int w = 1; w < len; ++w) {
        const int cells = len - w;
        const int pairs = (cells + 1) >> 1;
        if (pairs > 64)      stepw2<EXPM, 3>(SL, pot, sbr, EG, SGh, w, cells, tid);
        else if (pairs > 32) stepw2<EXPM, 4>(SL, pot, sbr, EG, SGh, w, cells, tid);
        else if (pairs > 16) stepw2<EXPM, 5>(SL, pot, sbr, EG, SGh, w, cells, tid);
        else                 stepw2<EXPM, 6>(SL, pot, sbr, EG, SGh, w, cells, tid);
        __syncthreads();
    }
}

// ---------------- kernel 3: all three CKY inside passes ----------------
__global__ __launch_bounds__(1024, 1)
void cky_all(float* __restrict__ W, const int* __restrict__ lengths) {
    __shared__ float SL[36864];           // 144 KB triangular chart
    const int bx = blockIdx.x;
    const int p = bx >> 4, b = bx & 15;
    const int tid = threadIdx.x;
    int len = lengths[b];
    if (len < 1) len = 1;
    if (len > N_) len = N_;
    float* zres = W + POTS_OFF + 9 * ANN_;

    if (p == 0) {
        const float* pot = W + POTS_OFF + 0 * ANN_ + b * NN_;
        const float* sbr = W + POTS_OFF + 1 * ANN_ + b * NN_;
        float* EG2 = W + POTS_OFF + 4 * ANN_ + b * (NN_ * 2);   // float2 chart
        float* SGh = W + POTS_OFF + 6 * ANN_ + b * NN_;
        cky_loop<true>(SL, pot, sbr, EG2, SGh, len, tid);
        if (tid == 0) {
            zres[b]      = SL[lds_addr(0, len - 1)];   // logZ_full (log2 units)
            zres[48 + b] = SGh[len - 1];               // E[sum sbar] (nat units)
        }
    } else {
        const float* pot = W + POTS_OFF + (p == 1 ? 2 : 3) * ANN_ + b * NN_;
        float* EG = W + POTS_OFF + (p == 1 ? 7 : 8) * ANN_ + b * NN_;
        cky_loop<false>(SL, pot, nullptr, EG, nullptr, len, tid);
        if (tid == 0) zres[p * 16 + b] = SL[lds_addr(0, len - 1)];
    }
}

// ---------------- kernel 4: combine outputs ----------------
__global__ void combine_kernel(const float* __restrict__ W, float* __restrict__ out) {
    int b = threadIdx.x;
    if (b >= B_) return;
    const float* zres = W + POTS_OFF + 9 * ANN_;
    float zf = zres[b], zs = zres[16 + b], zp = zres[32 + b], hr = zres[48 + b];
    out[b]          = (zp - zf) * LN2_F;   // log_prob
    out[16 + b]     = (zs - zf) * LN2_F;   // log_prob_smooth
    out[32 + b]     = zf * LN2_F - hr;     // entropy = z_full - E[sum sbar]
}

extern "C" void kernel_launch(void* const* d_in, const int* in_sizes, int n_in,
                              void* d_out, int out_size, void* d_ws, size_t ws_size,
                              hipStream_t stream) {
    const float* lp      = (const float*)d_in[0];
    // d_in[1] (mask) is unused by the reference
    const int*   lengths = (const int*)d_in[2];
    const float* evm     = (const float*)d_in[3];
    float*  W    = (float*)d_ws;
    double* part = (double*)d_ws;
    float*  stats = W + 2048;
    float*  out  = (float*)d_out;

    stats_partial<<<B_ * 32, 256, 0, stream>>>(lp, part);
    stats_final<<<1, 64, 0, stream>>>(part, stats);
    pots_kernel<<<(B_ * NN_) / 256, 256, 0, stream>>>(lp, evm, stats, W);
    cky_all<<<3 * B_, 1024, 0, stream>>>(W, lengths);
    combine_kernel<<<1, 64, 0, stream>>>(W, out);
}

// Round 7
// 949.635 us; speedup vs baseline: 1.1078x; 1.1078x over previous
//
#include <hip/hip_runtime.h>
#include <math.h>

#define B_ 16
#define N_ 256
#define L_ 32
#define NN_ (N_*N_)          // 65536
#define NNL_ (NN_*L_)        // 2097152 elements per batch
#define ANN_ (B_*NN_)        // 1048576
#define POTS_OFF 4096        // float offset where big arrays start
#define NEGINF -1.0e30f
#define LOG2E_F 1.4426950408889634f
#define LN2_F   0.6931471805599453f

typedef float v2f __attribute__((ext_vector_type(2)));

// Fast base-2 transcendentals (v_exp_f32 / v_log_f32). Math verified r2/r3.
#if __has_builtin(__builtin_amdgcn_exp2f)
#define EX2(x) __builtin_amdgcn_exp2f(x)
#else
#define EX2(x) exp2f(x)
#endif
#if __has_builtin(__builtin_amdgcn_logf)
#define LG2(x) __builtin_amdgcn_logf(x)
#else
#define LG2(x) log2f(x)
#endif

__device__ __forceinline__ v2f f4lo(float4 v) { v2f r; r.x = v.x; r.y = v.y; return r; }
__device__ __forceinline__ v2f f4hi(float4 v) { v2f r; r.x = v.z; r.y = v.w; return r; }
__device__ __forceinline__ v2f v2max(v2f a, v2f b) { return __builtin_elementwise_max(a, b); }

// ws float layout (float* W = (float*)d_ws):
//   [0 .. 2048)  : 1024 doubles — stats partials [B][32][2]
//   [2048..2080) : stats (mean, invstd) per batch
//   W + POTS_OFF + k*ANN_:
//     0: pot1 (start-major, log2 units)   1: sbar (start-major, nat units)
//     2: pot2 (log2)   3: pot3 (log2)
//     4: EGe p0 (end-major, REVERSED cols)  5: EGh p0 (same)  6: SGh p0 (start-major)
//     7: EGe p1   8: EGe p2
//   W + POTS_OFF + 9*ANN_: zres[64]
//
// r3-verified structure (567us r5): 48 blocks x 1024 threads, LEFT ev chart in
// LDS (triangular, XOR-swizzled, ds_read_b128), RIGHT from global end-major
// rows, one __syncthreads per width step.
// r4 lesson: hand pipelining regresses. r5: fewer transcendentals neutral.
// r6: 2-cell ILP regressed (+59% VALU) => critical block is ISSUE-bound.
// r7: cut issue slots with packed fp32 (v_pk_* via ext_vector float2).
// End-major charts store col slot = N-1-c so the 4-split window reads splits
// in FORWARD order -> natural v2 pairs with the LDS left granule (no swap
// movs), and the tail window overflows forward into mapped ws (masked).

// ---------------- kernel 1a: per-batch sum/sumsq partials ----------------
__global__ void stats_partial(const float* __restrict__ lp, double* __restrict__ part) {
    int blk = blockIdx.x;            // 0..511 = B*32
    int b = blk >> 5, seg = blk & 31;
    const float4* p4 = (const float4*)(lp + (size_t)b * NNL_ + (size_t)seg * (NNL_ / 32));
    double s = 0.0, ss = 0.0;
    for (int idx = threadIdx.x; idx < (NNL_ / 32 / 4); idx += 256) {
        float4 v = p4[idx];
        s  += (double)v.x + (double)v.y + (double)v.z + (double)v.w;
        ss += (double)v.x * v.x + (double)v.y * v.y + (double)v.z * v.z + (double)v.w * v.w;
    }
    __shared__ double sh0[256], sh1[256];
    sh0[threadIdx.x] = s; sh1[threadIdx.x] = ss;
    __syncthreads();
    for (int off = 128; off > 0; off >>= 1) {
        if (threadIdx.x < off) {
            sh0[threadIdx.x] += sh0[threadIdx.x + off];
            sh1[threadIdx.x] += sh1[threadIdx.x + off];
        }
        __syncthreads();
    }
    if (threadIdx.x == 0) { part[blk * 2] = sh0[0]; part[blk * 2 + 1] = sh1[0]; }
}

// ---------------- kernel 1b: finalize mean/invstd ----------------
__global__ void stats_final(const double* __restrict__ part, float* __restrict__ stats) {
    int b = threadIdx.x;
    if (b >= B_) return;
    double s = 0.0, ss = 0.0;
    for (int k = 0; k < 32; ++k) { s += part[(b * 32 + k) * 2]; ss += part[(b * 32 + k) * 2 + 1]; }
    double n = (double)NNL_;
    double mean = s / n;
    double var = (ss - s * s / n) / (n - 1.0);
    stats[b * 2]     = (float)mean;
    stats[b * 2 + 1] = (float)(1.0 / sqrt(var));
}

// ---------------- kernel 2: label-lse -> span potentials ----------------
// One thread per VALID cell via mirror pairing: thread (i<128, w) handles
// (i,w) if i+w<=255 else (255-i,255-w); i+w==255 handles both. ~100%
// utilization (r5 wasted 50% of threads on the empty triangle half).
__device__ __forceinline__ void pots_cell(
    const float* __restrict__ lp, const float* __restrict__ evm,
    float mean, float invstd, int b, int i, int w, float* __restrict__ W)
{
    int j = i + w;
    const float4* xp = (const float4*)(lp  + ((size_t)(b * NN_ + i * N_ + j) << 5));
    const float4* ep = (const float4*)(evm + ((size_t)(b * NN_ + i * N_ + j) << 5));
    float m1 = NEGINF, s1 = 0.f, n1 = 0.f;
    float m2 = NEGINF, s2 = 0.f;
    float m3 = NEGINF, s3 = 0.f;
#pragma unroll
    for (int c = 0; c < 8; ++c) {
        float4 xv = xp[c];
        float4 em = ep[c];
        float x0 = (xv.x - mean) * invstd, x1 = (xv.y - mean) * invstd;
        float x2 = (xv.z - mean) * invstd, x3 = (xv.w - mean) * invstd;
        {
            float cm = fmaxf(fmaxf(x0, x1), fmaxf(x2, x3));
            float nm = fmaxf(m1, cm);
            float sc = __expf(m1 - nm);
            float e0 = __expf(x0 - nm), e1 = __expf(x1 - nm);
            float e2 = __expf(x2 - nm), e3 = __expf(x3 - nm);
            s1 = s1 * sc + (e0 + e1 + e2 + e3);
            n1 = n1 * sc + (e0 * x0 + e1 * x1 + e2 * x2 + e3 * x3);
            m1 = nm;
        }
        {
            float y0 = x0 + __logf(fmaf(em.x, 0.9f, 0.1f) + 1e-10f);
            float y1 = x1 + __logf(fmaf(em.y, 0.9f, 0.1f) + 1e-10f);
            float y2 = x2 + __logf(fmaf(em.z, 0.9f, 0.1f) + 1e-10f);
            float y3 = x3 + __logf(fmaf(em.w, 0.9f, 0.1f) + 1e-10f);
            float cm = fmaxf(fmaxf(y0, y1), fmaxf(y2, y3));
            float nm = fmaxf(m2, cm);
            float sc = __expf(m2 - nm);
            s2 = s2 * sc + __expf(y0 - nm) + __expf(y1 - nm) + __expf(y2 - nm) + __expf(y3 - nm);
            m2 = nm;
        }
        {
            float z0 = fmaf(em.x, 1e6f, x0 - 1e6f);
            float z1 = fmaf(em.y, 1e6f, x1 - 1e6f);
            float z2 = fmaf(em.z, 1e6f, x2 - 1e6f);
            float z3 = fmaf(em.w, 1e6f, x3 - 1e6f);
            float cm = fmaxf(fmaxf(z0, z1), fmaxf(z2, z3));
            float nm = fmaxf(m3, cm);
            float sc = __expf(m3 - nm);
            s3 = s3 * sc + __expf(z0 - nm) + __expf(z1 - nm) + __expf(z2 - nm) + __expf(z3 - nm);
            m3 = nm;
        }
    }
    int o = b * NN_ + i * N_ + w;                // START-major layout
    W[POTS_OFF + 0 * ANN_ + o] = (m1 + __logf(s1)) * LOG2E_F;
    W[POTS_OFF + 1 * ANN_ + o] = n1 / s1;
    W[POTS_OFF + 2 * ANN_ + o] = (m2 + __logf(s2)) * LOG2E_F;
    W[POTS_OFF + 3 * ANN_ + o] = (m3 + __logf(s3)) * LOG2E_F;
}

__global__ __launch_bounds__(256)
void pots_kernel(const float* __restrict__ lp, const float* __restrict__ evm,
                 const float* __restrict__ stats, float* __restrict__ W) {
    int t = blockIdx.x * 256 + threadIdx.x;     // 0 .. B*NN/2-1
    int b = t >> 15;
    int rem = t & (NN_ / 2 - 1);
    int i = rem >> 8;                            // 0..127
    int w = rem & (N_ - 1);
    float mean = stats[b * 2], invstd = stats[b * 2 + 1];
    int sum = i + w;
    if (sum <= N_ - 1) pots_cell(lp, evm, mean, invstd, b, i, w, W);
    else               pots_cell(lp, evm, mean, invstd, b, N_ - 1 - i, N_ - 1 - w, W);
    if (sum == N_ - 1) pots_cell(lp, evm, mean, invstd, b, N_ - 1 - i, N_ - 1 - w, W);
}

// ---------------- LDS triangular chart addressing ----------------
// Start-major: row i holds widths u = 0..(255-i), capacity padded to 32-float
// (8-granule) multiples: cap32(i) = 32*(8 - (i>>5)). Total = 36864 floats
// (144 KB). Swizzle: granule index XOR (i&7).
__device__ __forceinline__ int lds_base(int i) {
    int a = i >> 5, c = i & 31;
    return ((8 * a - ((a * (a - 1)) >> 1)) << 10) + ((c * (8 - a)) << 5);
}
__device__ __forceinline__ int lds_addr(int i, int u) {
    return lds_base(i) + ((((u >> 2) ^ (i & 7)) << 2) | (u & 3));
}

// unaligned (4B-aligned) 16B global load
__device__ __forceinline__ float4 ld4u(const float* p) {
    float4 v; __builtin_memcpy(&v, p, 16); return v;
}

// ---------------- one width step ----------------
// group = cell (G = 2^LOGG consecutive tids). Lane l owns granules mu = l,
// l+G, ...; hot loop = 2 granules / iteration, single rescale, all pair math
// in packed float2 (v_pk_add/max/fma_f32). End-major charts are col-REVERSED
// (slot = N-1-c), so egE[(N-w)+u] walks splits u FORWARD: left LDS granule
// and right window pair naturally with no component swaps.
template <bool EXPM, int LOGG>
__device__ __forceinline__ void stepw(
    float* __restrict__ SL,
    const float* __restrict__ pot, const float* __restrict__ sbr,
    float* __restrict__ EGe, float* __restrict__ EGh, float* __restrict__ SGh,
    const int w, const int cells, const int tid)
{
    constexpr int G = 1 << LOGG;
    const int group = tid >> LOGG;
    const int l = tid & (G - 1);
    if (group >= cells) return;
    const int i = group;
    const int j = i + w;
    const int ib = lds_base(i);
    const int isw = i & 7;
    const float* egE = EGe + j * N_ + (N_ - w);   // index by split u directly
    const float* egH = nullptr;
    const float* sgH = nullptr;
    if constexpr (EXPM) { egH = EGh + j * N_ + (N_ - w); sgH = SGh + i * N_; }
    // epilogue inputs: issue early, consume late
    const float pw = pot[i * N_ + w];
    float sb = 0.f;
    if constexpr (EXPM) sb = sbr[i * N_ + w];

    const int F = w >> 2;        // full granules
    const int r = w & 3;         // tail valid count (0 => no tail)

    float m = NEGINF;
    v2f s2; s2.x = 0.f; s2.y = 0.f;
    v2f n2; n2.x = 0.f; n2.y = 0.f;

    int mu = l;
    // ---- hot loop: 2 granules, one rescale, packed math ----
    for (; mu + G < F; mu += 2 * G) {
        const int ua = mu << 2, ub = (mu + G) << 2;
        const float4 La = *(const float4*)&SL[ib + ((mu ^ isw) << 2)];
        const float4 Lb = *(const float4*)&SL[ib + (((mu + G) ^ isw) << 2)];
        const float4 Ra = ld4u(egE + ua);
        const float4 Rb = ld4u(egE + ub);
        v2f ea0 = f4lo(La) + f4lo(Ra);
        v2f ea1 = f4hi(La) + f4hi(Ra);
        v2f eb0 = f4lo(Lb) + f4lo(Rb);
        v2f eb1 = f4hi(Lb) + f4hi(Rb);
        v2f mx = v2max(v2max(ea0, ea1), v2max(eb0, eb1));
        float nm = fmaxf(m, fmaxf(mx.x, mx.y));
        float sc = EX2(m - nm);
        v2f nmv; nmv.x = nm; nmv.y = nm;
        v2f scv; scv.x = sc; scv.y = sc;
        v2f d0 = ea0 - nmv, d1 = ea1 - nmv, d2 = eb0 - nmv, d3 = eb1 - nmv;
        v2f E0; E0.x = EX2(d0.x); E0.y = EX2(d0.y);
        v2f E1; E1.x = EX2(d1.x); E1.y = EX2(d1.y);
        v2f E2; E2.x = EX2(d2.x); E2.y = EX2(d2.y);
        v2f E3; E3.x = EX2(d3.x); E3.y = EX2(d3.y);
        s2 = s2 * scv + ((E0 + E1) + (E2 + E3));
        if constexpr (EXPM) {
            const float4 Ha = *(const float4*)(sgH + ua);
            const float4 Hb = *(const float4*)(sgH + ub);
            const float4 Qa = ld4u(egH + ua);
            const float4 Qb = ld4u(egH + ub);
            v2f ha0 = f4lo(Ha) + f4lo(Qa);
            v2f ha1 = f4hi(Ha) + f4hi(Qa);
            v2f hb0 = f4lo(Hb) + f4lo(Qb);
            v2f hb1 = f4hi(Hb) + f4hi(Qb);
            v2f t = E0 * ha0 + E1 * ha1;
            v2f u = E2 * hb0 + E3 * hb1;
            n2 = n2 * scv + (t + u);
        }
        m = nm;
    }
    // ---- leftover full granule (0 or 1 per lane) ----
    if (mu < F) {
        const int u0 = mu << 2;
        const float4 Lv = *(const float4*)&SL[ib + ((mu ^ isw) << 2)];
        const float4 Rv = ld4u(egE + u0);
        v2f e0 = f4lo(Lv) + f4lo(Rv);
        v2f e1 = f4hi(Lv) + f4hi(Rv);
        v2f mx = v2max(e0, e1);
        float nm = fmaxf(m, fmaxf(mx.x, mx.y));
        float sc = EX2(m - nm);
        v2f nmv; nmv.x = nm; nmv.y = nm;
        v2f scv; scv.x = sc; scv.y = sc;
        v2f d0 = e0 - nmv, d1 = e1 - nmv;
        v2f E0; E0.x = EX2(d0.x); E0.y = EX2(d0.y);
        v2f E1; E1.x = EX2(d1.x); E1.y = EX2(d1.y);
        s2 = s2 * scv + (E0 + E1);
        if constexpr (EXPM) {
            const float4 Hl = *(const float4*)(sgH + u0);
            const float4 Qv = ld4u(egH + u0);
            v2f h0 = f4lo(Hl) + f4lo(Qv);
            v2f h1 = f4hi(Hl) + f4hi(Qv);
            n2 = n2 * scv + (E0 * h0 + E1 * h1);
        }
        m = nm;
    }
    // ---- masked tail granule (index F, r in {1,2,3} valid splits) ----
    // Forward window may read past row j's end (next row / zres, mapped ws):
    // garbage could be Inf/NaN -> mask e to NEGINF and h to 0 before use.
    if (r && l == (F & (G - 1))) {
        const int u0 = F << 2;
        const float4 Lv = *(const float4*)&SL[ib + ((F ^ isw) << 2)];
        const float4 Rv = ld4u(egE + u0);
        float e0 = Lv.x + Rv.x;
        float e1 = (r > 1) ? (Lv.y + Rv.y) : NEGINF;
        float e2 = (r > 2) ? (Lv.z + Rv.z) : NEGINF;
        float nm = fmaxf(m, fmaxf(fmaxf(e0, e1), e2));
        float sc = EX2(m - nm);
        float E0 = EX2(e0 - nm), E1 = EX2(e1 - nm), E2 = EX2(e2 - nm);
        v2f scv; scv.x = sc; scv.y = sc;
        v2f add; add.x = E0 + E2; add.y = E1;
        s2 = s2 * scv + add;
        if constexpr (EXPM) {
            const float4 Hl = *(const float4*)(sgH + u0);
            const float4 Qv = ld4u(egH + u0);
            float h0 = Hl.x + Qv.x;
            float h1 = (r > 1) ? (Hl.y + Qv.y) : 0.f;
            float h2 = (r > 2) ? (Hl.z + Qv.z) : 0.f;
            v2f na; na.x = E0 * h0 + E2 * h2; na.y = E1 * h1;
            n2 = n2 * scv + na;
        }
        m = nm;
    }

    // horizontal collapse, then merge across the G lanes of the group
    float s = s2.x + s2.y;
    float n = 0.f;
    if constexpr (EXPM) n = n2.x + n2.y;
#pragma unroll
    for (int k = 1; k < G; k <<= 1) {
        float mo = __shfl_xor(m, k);
        float so = __shfl_xor(s, k);
        float no = 0.f;
        if constexpr (EXPM) no = __shfl_xor(n, k);
        float nm = fmaxf(m, mo);
        float a  = EX2(m - nm), bb = EX2(mo - nm);
        s = s * a + so * bb;
        if constexpr (EXPM) n = n * a + no * bb;
        m = nm;
    }
    if (l == 0) {
        float v = pw + m + LG2(s);
        SL[lds_addr(i, w)] = v;
        EGe[j * N_ + (N_ - 1 - w)] = v;
        if constexpr (EXPM) {
            float hv = sb + n / s;
            EGh[j * N_ + (N_ - 1 - w)] = hv;
            SGh[i * N_ + w] = hv;
        }
    }
}

template <bool EXPM>
__device__ __forceinline__ void cky_loop(
    float* __restrict__ SL,
    const float* __restrict__ pot, const float* __restrict__ sbr,
    float* __restrict__ EGe, float* __restrict__ EGh, float* __restrict__ SGh,
    const int len, const int tid)
{
    // width-0 diagonal (reversed col slot for w=0 is N-1)
    for (int i = tid; i < len; i += 1024) {
        float v = pot[i * N_];
        SL[lds_addr(i, 0)] = v;
        EGe[i * N_ + (N_ - 1)] = v;
        if constexpr (EXPM) {
            float h0 = sbr[i * N_];
            EGh[i * N_ + (N_ - 1)] = h0;
            SGh[i * N_] = h0;
        }
    }
    __syncthreads();
    for (int w = 1; w < len; ++w) {
        const int cells = len - w;
        if (cells > 128)      stepw<EXPM, 2>(SL, pot, sbr, EGe, EGh, SGh, w, cells, tid);
        else if (cells > 64)  stepw<EXPM, 3>(SL, pot, sbr, EGe, EGh, SGh, w, cells, tid);
        else if (cells > 32)  stepw<EXPM, 4>(SL, pot, sbr, EGe, EGh, SGh, w, cells, tid);
        else if (cells > 16)  stepw<EXPM, 5>(SL, pot, sbr, EGe, EGh, SGh, w, cells, tid);
        else                  stepw<EXPM, 6>(SL, pot, sbr, EGe, EGh, SGh, w, cells, tid);
        __syncthreads();
    }
}

// ---------------- kernel 3: all three CKY inside passes ----------------
__global__ __launch_bounds__(1024, 1)
void cky_all(float* __restrict__ W, const int* __restrict__ lengths) {
    __shared__ float SL[36864];           // 144 KB triangular chart
    const int bx = blockIdx.x;
    const int p = bx >> 4, b = bx & 15;
    const int tid = threadIdx.x;
    int len = lengths[b];
    if (len < 1) len = 1;
    if (len > N_) len = N_;
    float* zres = W + POTS_OFF + 9 * ANN_;

    if (p == 0) {
        const float* pot = W + POTS_OFF + 0 * ANN_ + b * NN_;
        const float* sbr = W + POTS_OFF + 1 * ANN_ + b * NN_;
        float* EGe = W + POTS_OFF + 4 * ANN_ + b * NN_;
        float* EGh = W + POTS_OFF + 5 * ANN_ + b * NN_;
        float* SGh = W + POTS_OFF + 6 * ANN_ + b * NN_;
        cky_loop<true>(SL, pot, sbr, EGe, EGh, SGh, len, tid);
        if (tid == 0) {
            zres[b]      = SL[lds_addr(0, len - 1)];   // logZ_full (log2 units)
            zres[48 + b] = SGh[len - 1];               // E[sum sbar] (nat units)
        }
    } else {
        const float* pot = W + POTS_OFF + (p == 1 ? 2 : 3) * ANN_ + b * NN_;
        float* EGe = W + POTS_OFF + (p == 1 ? 7 : 8) * ANN_ + b * NN_;
        cky_loop<false>(SL, pot, nullptr, EGe, nullptr, nullptr, len, tid);
        if (tid == 0) zres[p * 16 + b] = SL[lds_addr(0, len - 1)];
    }
}

// ---------------- kernel 4: combine outputs ----------------
__global__ void combine_kernel(const float* __restrict__ W, float* __restrict__ out) {
    int b = threadIdx.x;
    if (b >= B_) return;
    const float* zres = W + POTS_OFF + 9 * ANN_;
    float zf = zres[b], zs = zres[16 + b], zp = zres[32 + b], hr = zres[48 + b];
    out[b]          = (zp - zf) * LN2_F;   // log_prob
    out[16 + b]     = (zs - zf) * LN2_F;   // log_prob_smooth
    out[32 + b]     = zf * LN2_F - hr;     // entropy = z_full - E[sum sbar]
}

extern "C" void kernel_launch(void* const* d_in, const int* in_sizes, int n_in,
                              void* d_out, int out_size, void* d_ws, size_t ws_size,
                              hipStream_t stream) {
    const float* lp      = (const float*)d_in[0];
    // d_in[1] (mask) is unused by the reference
    const int*   lengths = (const int*)d_in[2];
    const float* evm     = (const float*)d_in[3];
    float*  W    = (float*)d_ws;
    double* part = (double*)d_ws;
    float*  stats = W + 2048;
    float*  out  = (float*)d_out;

    stats_partial<<<B_ * 32, 256, 0, stream>>>(lp, part);
    stats_final<<<1, 64, 0, stream>>>(part, stats);
    pots_kernel<<<(B_ * NN_ / 2) / 256, 256, 0, stream>>>(lp, evm, stats, W);
    cky_all<<<3 * B_, 1024, 0, stream>>>(W, lengths);
    combine_kernel<<<1, 64, 0, stream>>>(W, out);
}